// Round 10
// baseline (646.662 us; speedup 1.0000x reference)
//
#include <hip/hip_runtime.h>

#define H   128

typedef __attribute__((ext_vector_type(8))) short short8;
typedef __attribute__((ext_vector_type(4))) float f32x4;

__device__ __forceinline__ unsigned int bfr(float f) {
  unsigned int u = __float_as_uint(f);
  return (u + 0x7fffu + ((u >> 16) & 1u)) >> 16;
}
__device__ __forceinline__ float bf_lo(unsigned int d) {
  return __uint_as_float(d << 16);
}
__device__ __forceinline__ float bf_hi(unsigned int d) {
  return __uint_as_float(d & 0xffff0000u);
}

// ---------------- node encoder: h2 = bf16(x @ node_w + node_b) -------------
__global__ __launch_bounds__(128) void node_enc(const float* __restrict__ x,
    const float* __restrict__ w, const float* __restrict__ b,
    unsigned int* __restrict__ h2, int N) {
  int row = blockIdx.x;
  if (row >= N) return;
  int j = threadIdx.x;
  __shared__ float xs[64];
  if (j < 64) xs[j] = x[(size_t)row * 64 + j];
  __syncthreads();
  float acc = b[j];
#pragma unroll
  for (int k = 0; k < 64; ++k) acc = fmaf(xs[k], w[k * H + j], acc);
  float part = __shfl_down(acc, 1, 64);
  if ((j & 1) == 0) {
    unsigned int d = bfr(acc) | (bfr(part) << 16);
    h2[(size_t)row * 64 + (j >> 1)] = d;
  }
}

// ---------------- CSR build: degree count ----------------------------------
__global__ __launch_bounds__(256) void count_deg(const int* __restrict__ dst,
    int* __restrict__ cnt, int E) {
  int e = blockIdx.x * 256 + threadIdx.x;
  if (e < E) atomicAdd(&cnt[dst[e]], 1);
}

// ---------------- scan pass 1 ----------------------------------------------
__global__ __launch_bounds__(256) void block_sum(const int* __restrict__ cnt,
    int* __restrict__ bsum, int N) {
  int t = threadIdx.x;
  int i = blockIdx.x * 256 + t;
  int v = (i < N) ? cnt[i] : 0;
#pragma unroll
  for (int o = 32; o > 0; o >>= 1) v += __shfl_down(v, o, 64);
  __shared__ int wt[4];
  if ((t & 63) == 0) wt[t >> 6] = v;
  __syncthreads();
  if (t == 0) bsum[blockIdx.x] = wt[0] + wt[1] + wt[2] + wt[3];
}

// ---------------- scan pass 2 ----------------------------------------------
__global__ __launch_bounds__(1024) void scan_bsum(const int* __restrict__ bsum,
    int* __restrict__ bbase, int nb) {
  __shared__ int s[1024];
  int t = threadIdx.x;
  int v = (t < nb) ? bsum[t] : 0;
  s[t] = v;
  __syncthreads();
  for (int o = 1; o < 1024; o <<= 1) {
    int u = (t >= o) ? s[t - o] : 0;
    __syncthreads();
    s[t] += u;
    __syncthreads();
  }
  if (t < nb) bbase[t] = s[t] - v;
}

// ---------------- scan pass 3 ----------------------------------------------
__global__ __launch_bounds__(256) void scan_pass(const int* __restrict__ cnt,
    const int* __restrict__ bbase, int* __restrict__ off,
    int* __restrict__ cursor, int N) {
  int t = threadIdx.x;
  int i = blockIdx.x * 256 + t;
  int v = (i < N) ? cnt[i] : 0;
  int lane = t & 63;
  int incl = v;
#pragma unroll
  for (int o = 1; o < 64; o <<= 1) {
    int u = __shfl_up(incl, o, 64);
    if (lane >= o) incl += u;
  }
  __shared__ int wtot[4];
  int w = t >> 6;
  if (lane == 63) wtot[w] = incl;
  __syncthreads();
  if (t == 0) {
    int run = 0;
#pragma unroll
    for (int k = 0; k < 4; ++k) { int tmp = wtot[k]; wtot[k] = run; run += tmp; }
  }
  __syncthreads();
  int excl = incl - v + wtot[w] + bbase[blockIdx.x];
  if (i < N) { off[i] = excl; cursor[i] = excl; }
  if (i == N - 1) off[N] = excl + v;
}

// ---------------- CSR build: scatter (also records dst per slot) -----------
__global__ __launch_bounds__(256) void scatter_csr(const int* __restrict__ src,
    const int* __restrict__ dst, int* __restrict__ cursor,
    int* __restrict__ perm, int* __restrict__ src_perm,
    int* __restrict__ dst_perm, int E) {
  int e = blockIdx.x * 256 + threadIdx.x;
  if (e < E) {
    int d = dst[e];
    int pos = atomicAdd(&cursor[d], 1);
    perm[pos] = e;
    src_perm[pos] = src[e];
    dst_perm[pos] = d;
  }
}

// ---------------- weight pack: fp32 [128][128] -> bf16 MFMA-B fragments ----
__global__ __launch_bounds__(256) void wpack(const float* __restrict__ w1,
    const float* __restrict__ w2, unsigned short* __restrict__ wp, int L) {
  int idx = blockIdx.x * 256 + threadIdx.x;
  int total = L * 2 * 16384;
  if (idx >= total) return;
  int j    = idx & 7;
  int lane = (idx >> 3) & 63;
  int ct   = (idx >> 9) & 7;
  int kt   = (idx >> 12) & 3;
  int mat  = idx >> 14;
  int l = mat >> 1, which = mat & 1;
  const float* w = (which == 0 ? w1 : w2) + (size_t)l * H * H;
  int k = kt * 32 + (lane >> 4) * 8 + j;
  int n = ct * 16 + (lane & 15);
  wp[idx] = (unsigned short)bfr(w[k * H + n]);
}

// ---- edge-balanced aggregation: z[n] += sum_{e->n} relu(h[src]+ea@ew+eb) --
// Each wave owns CH contiguous permuted edges (perfect balance). dst-sorted
// runs accumulate in registers; flush to z (fp32, pre-zeroed) via atomicAdd
// on node change. Wave-uniform scalar loads for perm/src/dst/ea.
__global__ __launch_bounds__(256) void aggr_chunk(const float* __restrict__ ea,
    const float* __restrict__ ew, const float* __restrict__ eb,
    const int* __restrict__ perm, const int* __restrict__ src_perm,
    const int* __restrict__ dst_perm, const unsigned int* __restrict__ h2,
    float* __restrict__ z, int E, int CH) {
  int wv = blockIdx.x * 4 + (threadIdx.x >> 6);
  int lane = threadIdx.x & 63;
  int i0 = wv * CH;
  int i1 = min(E, i0 + CH);
  if (i0 >= i1) return;
  int c = lane * 2;
  float2 wc[16];
#pragma unroll
  for (int k = 0; k < 16; ++k) wc[k] = *(const float2*)&ew[k * H + c];
  float2 bias = *(const float2*)&eb[c];
  int cur = __builtin_amdgcn_readfirstlane(dst_perm[i0]);
  float ax = 0.f, ay = 0.f;
  int i = i0;
  for (; i + 2 <= i1; i += 2) {
    int e0 = __builtin_amdgcn_readfirstlane(perm[i]);
    int e1 = __builtin_amdgcn_readfirstlane(perm[i + 1]);
    int s0 = __builtin_amdgcn_readfirstlane(src_perm[i]);
    int s1 = __builtin_amdgcn_readfirstlane(src_perm[i + 1]);
    int d0 = __builtin_amdgcn_readfirstlane(dst_perm[i]);
    int d1 = __builtin_amdgcn_readfirstlane(dst_perm[i + 1]);
    unsigned int hv0 = h2[(size_t)s0 * 64 + lane];
    unsigned int hv1 = h2[(size_t)s1 * 64 + lane];
    const float* a0 = ea + (size_t)e0 * 16;
    const float* a1 = ea + (size_t)e1 * 16;
    float x0 = bias.x, y0 = bias.y, x1 = bias.x, y1 = bias.y;
#pragma unroll
    for (int k = 0; k < 16; ++k) {
      float a0k = a0[k], a1k = a1[k];
      x0 = fmaf(a0k, wc[k].x, x0);
      y0 = fmaf(a0k, wc[k].y, y0);
      x1 = fmaf(a1k, wc[k].x, x1);
      y1 = fmaf(a1k, wc[k].y, y1);
    }
    if (d0 != cur) {
      atomicAdd(&z[(size_t)cur * H + c], ax);
      atomicAdd(&z[(size_t)cur * H + c + 1], ay);
      ax = ay = 0.f;
      cur = d0;
    }
    ax += fmaxf(x0 + bf_lo(hv0), 0.f);
    ay += fmaxf(y0 + bf_hi(hv0), 0.f);
    if (d1 != cur) {
      atomicAdd(&z[(size_t)cur * H + c], ax);
      atomicAdd(&z[(size_t)cur * H + c + 1], ay);
      ax = ay = 0.f;
      cur = d1;
    }
    ax += fmaxf(x1 + bf_lo(hv1), 0.f);
    ay += fmaxf(y1 + bf_hi(hv1), 0.f);
  }
  if (i < i1) {
    int e0 = __builtin_amdgcn_readfirstlane(perm[i]);
    int s0 = __builtin_amdgcn_readfirstlane(src_perm[i]);
    int d0 = __builtin_amdgcn_readfirstlane(dst_perm[i]);
    unsigned int hv0 = h2[(size_t)s0 * 64 + lane];
    const float* a0 = ea + (size_t)e0 * 16;
    float x0 = bias.x, y0 = bias.y;
#pragma unroll
    for (int k = 0; k < 16; ++k) {
      float a0k = a0[k];
      x0 = fmaf(a0k, wc[k].x, x0);
      y0 = fmaf(a0k, wc[k].y, y0);
    }
    if (d0 != cur) {
      atomicAdd(&z[(size_t)cur * H + c], ax);
      atomicAdd(&z[(size_t)cur * H + c + 1], ay);
      ax = ay = 0.f;
      cur = d0;
    }
    ax += fmaxf(x0 + bf_lo(hv0), 0.f);
    ay += fmaxf(y0 + bf_hi(hv0), 0.f);
  }
  atomicAdd(&z[(size_t)cur * H + c], ax);
  atomicAdd(&z[(size_t)cur * H + c + 1], ay);
}

// ---- MFMA GEMM1: t = bf16(z + h) @ w1 + b1 (fp32 out) + BN column sums ----
__global__ __launch_bounds__(256) void mlp1m(const float* __restrict__ z,
    const unsigned int* __restrict__ h2, const unsigned short* __restrict__ wp,
    const float* __restrict__ b1, float* __restrict__ tout,
    float* __restrict__ sum, float* __restrict__ sumsq, int N) {
  int tid = threadIdx.x;
  int wave = tid >> 6, lane = tid & 63;
  int q = lane >> 4, m = lane & 15;
  int r0 = blockIdx.x * 64 + wave * 16;
  int row = r0 + m;
  f32x4 acc[8];
#pragma unroll
  for (int ct = 0; ct < 8; ++ct) acc[ct] = (f32x4){0.f, 0.f, 0.f, 0.f};
#pragma unroll
  for (int kt = 0; kt < 4; ++kt) {
    int c0 = kt * 32 + q * 8;
    f32x4 z0 = *(const f32x4*)(z + (size_t)row * H + c0);
    f32x4 z1 = *(const f32x4*)(z + (size_t)row * H + c0 + 4);
    uint4 hh = *(const uint4*)(h2 + (size_t)row * 64 + (c0 >> 1));
    short8 a;
    a[0] = (short)bfr(z0[0] + bf_lo(hh.x));
    a[1] = (short)bfr(z0[1] + bf_hi(hh.x));
    a[2] = (short)bfr(z0[2] + bf_lo(hh.y));
    a[3] = (short)bfr(z0[3] + bf_hi(hh.y));
    a[4] = (short)bfr(z1[0] + bf_lo(hh.z));
    a[5] = (short)bfr(z1[1] + bf_hi(hh.z));
    a[6] = (short)bfr(z1[2] + bf_lo(hh.w));
    a[7] = (short)bfr(z1[3] + bf_hi(hh.w));
#pragma unroll
    for (int ct = 0; ct < 8; ++ct) {
      short8 b = *(const short8*)(wp + ((size_t)(kt * 8 + ct) * 64 + lane) * 8);
      acc[ct] = __builtin_amdgcn_mfma_f32_16x16x32_bf16(a, b, acc[ct], 0, 0, 0);
    }
  }
  __shared__ float red[2][H][16];
  int wq = wave * 4 + q;
#pragma unroll
  for (int ct = 0; ct < 8; ++ct) {
    int col = ct * 16 + m;
    float bias = b1[col];
    float s1 = 0.f, s2 = 0.f;
#pragma unroll
    for (int r = 0; r < 4; ++r) {
      int gr = r0 + q * 4 + r;
      float v = acc[ct][r] + bias;
      if (gr < N) {
        tout[(size_t)gr * H + col] = v;
        s1 += v;
        s2 += v * v;
      }
    }
    red[0][col][wq] = s1;
    red[1][col][wq] = s2;
  }
  __syncthreads();
  if (tid < H) {
    float a = 0.f, b = 0.f;
#pragma unroll
    for (int g = 0; g < 16; ++g) {
      a += red[0][tid][g];
      b += red[1][tid][g];
    }
    atomicAdd(&sum[tid], a);
    atomicAdd(&sumsq[tid], b);
  }
}

// ---- MFMA GEMM2 with fused BN-finalize prologue; bf16 h out or pool -------
__global__ __launch_bounds__(256) void mlp2m(const float* __restrict__ tin,
    const float* __restrict__ sums, const float* __restrict__ sumsqs,
    const float* __restrict__ bng, const float* __restrict__ bnb,
    const unsigned short* __restrict__ wp, const float* __restrict__ b2,
    unsigned short* __restrict__ hout, int N, float invN,
    const int* __restrict__ batch, float* __restrict__ pooled) {
  int tid = threadIdx.x;
  __shared__ float scs[H], shs[H];
  if (tid < H) {
    float mu = sums[tid] * invN;
    float var = sumsqs[tid] * invN - mu * mu;
    float inv = rsqrtf(var + 1e-5f);
    float sc = bng[tid] * inv;
    scs[tid] = sc;
    shs[tid] = bnb[tid] - mu * sc;
  }
  __syncthreads();
  int wave = tid >> 6, lane = tid & 63;
  int q = lane >> 4, m = lane & 15;
  int r0 = blockIdx.x * 64 + wave * 16;
  int row = r0 + m;
  f32x4 acc[8];
#pragma unroll
  for (int ct = 0; ct < 8; ++ct) acc[ct] = (f32x4){0.f, 0.f, 0.f, 0.f};
#pragma unroll
  for (int kt = 0; kt < 4; ++kt) {
    int c0 = kt * 32 + q * 8;
    f32x4 t0 = *(const f32x4*)(tin + (size_t)row * H + c0);
    f32x4 t1 = *(const f32x4*)(tin + (size_t)row * H + c0 + 4);
    short8 a;
#pragma unroll
    for (int j = 0; j < 4; ++j) {
      float v = fmaxf(fmaf(t0[j], scs[c0 + j], shs[c0 + j]), 0.f);
      a[j] = (short)bfr(v);
    }
#pragma unroll
    for (int j = 0; j < 4; ++j) {
      float v = fmaxf(fmaf(t1[j], scs[c0 + 4 + j], shs[c0 + 4 + j]), 0.f);
      a[4 + j] = (short)bfr(v);
    }
#pragma unroll
    for (int ct = 0; ct < 8; ++ct) {
      short8 b = *(const short8*)(wp + ((size_t)(kt * 8 + ct) * 64 + lane) * 8);
      acc[ct] = __builtin_amdgcn_mfma_f32_16x16x32_bf16(a, b, acc[ct], 0, 0, 0);
    }
  }
#pragma unroll
  for (int ct = 0; ct < 8; ++ct) {
    float bias = b2[ct * 16 + m];
#pragma unroll
    for (int r = 0; r < 4; ++r) acc[ct][r] = fmaxf(acc[ct][r] + bias, 0.f);
  }
  if (hout != nullptr) {
#pragma unroll
    for (int r = 0; r < 4; ++r) {
      int gr = r0 + q * 4 + r;
      if (gr < N) {
#pragma unroll
        for (int ct = 0; ct < 8; ++ct)
          hout[(size_t)gr * H + ct * 16 + m] = (unsigned short)bfr(acc[ct][r]);
      }
    }
  }
  if (pooled != nullptr) {
    int bprev = -1;
    float pa[8];
#pragma unroll
    for (int ct = 0; ct < 8; ++ct) pa[ct] = 0.f;
    for (int r = 0; r < 4; ++r) {
      int gr = r0 + q * 4 + r;
      if (gr >= N) break;
      int bb = batch[gr];
      if (bb != bprev && bprev >= 0) {
#pragma unroll
        for (int ct = 0; ct < 8; ++ct) {
          atomicAdd(&pooled[(size_t)bprev * H + ct * 16 + m], pa[ct]);
          pa[ct] = 0.f;
        }
      }
      bprev = bb;
#pragma unroll
      for (int ct = 0; ct < 8; ++ct) pa[ct] += acc[ct][r];
    }
    if (bprev >= 0) {
#pragma unroll
      for (int ct = 0; ct < 8; ++ct)
        atomicAdd(&pooled[(size_t)bprev * H + ct * 16 + m], pa[ct]);
    }
  }
}

// ---- final FC: out = pooled @ fc_w + fc_b ---------------------------------
__global__ __launch_bounds__(128) void fc_kernel(const float* __restrict__ pooled,
    const float* __restrict__ w, const float* __restrict__ b,
    float* __restrict__ out, int C) {
  int g = blockIdx.x;
  int j = threadIdx.x;
  __shared__ float p[H];
  p[j] = pooled[(size_t)g * H + j];
  __syncthreads();
  if (j < C) {
    float acc = b[j];
#pragma unroll 4
    for (int k = 0; k < H; ++k) acc = fmaf(p[k], w[k * C + j], acc);
    out[(size_t)g * C + j] = acc;
  }
}

extern "C" void kernel_launch(void* const* d_in, const int* in_sizes, int n_in,
                              void* d_out, int out_size, void* d_ws, size_t ws_size,
                              hipStream_t stream) {
  const float* x         = (const float*)d_in[0];
  const float* edge_attr = (const float*)d_in[1];
  const float* node_w    = (const float*)d_in[2];
  const float* node_b    = (const float*)d_in[3];
  const float* edge_w    = (const float*)d_in[4];
  const float* edge_b    = (const float*)d_in[5];
  const float* lin1_w    = (const float*)d_in[6];
  const float* lin1_b    = (const float*)d_in[7];
  const float* bn_g      = (const float*)d_in[8];
  const float* bn_b      = (const float*)d_in[9];
  const float* lin2_w    = (const float*)d_in[10];
  const float* lin2_b    = (const float*)d_in[11];
  const float* fc_w      = (const float*)d_in[12];
  const float* fc_b      = (const float*)d_in[13];
  const int*   edge_index= (const int*)d_in[14];
  const int*   batch     = (const int*)d_in[15];

  int N = in_sizes[0] / 64;       // 50000
  int E = in_sizes[1] / 16;       // 640000
  int C = in_sizes[13];           // 10
  int G = out_size / C;           // 512

  const int* src = edge_index;
  const int* dst = edge_index + E;

  int mblk = (N + 63) / 64;
  int Npad = mblk * 64;           // 50048

  float* t      = (float*)d_ws;              // [Npad,H] fp32
  float* z      = t + (size_t)Npad * H;      // [Npad,H] fp32
  float* pooled = z + (size_t)Npad * H;      // [G,H]
  float* sumsA  = pooled + (size_t)G * H;    // [3*256] (sum|sumsq per layer)
  unsigned int* h2 = (unsigned int*)(sumsA + 3 * 256);  // [Npad,64] bf16x2
  unsigned short* wp = (unsigned short*)(h2 + (size_t)Npad * 64);  // 6*16384
  int* cnt      = (int*)(wp + 6 * 16384);
  int* off      = cnt + N;
  int* cursor   = off + N + 1;
  int* src_perm = cursor + N;                // [E]
  int* dst_perm = src_perm + E;              // [E]
  int* perm     = dst_perm + E;              // [E]
  int* bsum     = perm + E;                  // [1024]
  int* bbase    = bsum + 1024;               // [1024]

  int nb = (N + 255) / 256;

  // --- CSR build + weight pack (every launch; deterministic) ---
  hipMemsetAsync(cnt, 0, (size_t)N * sizeof(int), stream);
  count_deg<<<(E + 255) / 256, 256, 0, stream>>>(dst, cnt, E);
  block_sum<<<nb, 256, 0, stream>>>(cnt, bsum, N);
  scan_bsum<<<1, 1024, 0, stream>>>(bsum, bbase, nb);
  scan_pass<<<nb, 256, 0, stream>>>(cnt, bbase, off, cursor, N);
  scatter_csr<<<(E + 255) / 256, 256, 0, stream>>>(src, dst, cursor, perm,
                                                   src_perm, dst_perm, E);
  wpack<<<(6 * 16384 + 255) / 256, 256, 0, stream>>>(lin1_w, lin2_w, wp, 3);
  hipMemsetAsync(sumsA, 0, 3 * 256 * sizeof(float), stream);

  node_enc<<<N, 128, 0, stream>>>(x, node_w, node_b, h2, N);

  const int NWAVE = 8192;
  int CH = (E + NWAVE - 1) / NWAVE;          // ~79 edges per wave
  int ablk = ( (E + CH - 1) / CH + 3 ) / 4;  // blocks of 4 waves

  for (int l = 0; l < 3; ++l) {
    hipMemsetAsync(z, 0, (size_t)N * H * sizeof(float), stream);
    aggr_chunk<<<ablk, 256, 0, stream>>>(edge_attr, edge_w, edge_b, perm,
                                         src_perm, dst_perm, h2, z, E, CH);
    mlp1m<<<mblk, 256, 0, stream>>>(z, h2, wp + (size_t)(l * 2 + 0) * 16384,
                                    lin1_b + (size_t)l * H, t,
                                    sumsA + l * 256, sumsA + l * 256 + 128, N);
    bool last = (l == 2);
    if (last) hipMemsetAsync(pooled, 0, (size_t)G * H * sizeof(float), stream);
    mlp2m<<<mblk, 256, 0, stream>>>(t, sumsA + l * 256, sumsA + l * 256 + 128,
                                    bn_g + (size_t)l * H, bn_b + (size_t)l * H,
                                    wp + (size_t)(l * 2 + 1) * 16384,
                                    lin2_b + (size_t)l * H,
                                    last ? nullptr : (unsigned short*)h2, N,
                                    1.0f / N, batch, last ? pooled : nullptr);
  }

  fc_kernel<<<G, 128, 0, stream>>>(pooled, fc_w, fc_b, (float*)d_out, C);
}